// Round 15
// baseline (751.043 us; speedup 1.0000x reference)
//
#include <hip/hip_runtime.h>
#include <hip/hip_bf16.h>
#include <math.h>

#define B_  4
#define S_  2048
#define DM  1024
#define H_  16

typedef __attribute__((ext_vector_type(8))) short short8;
typedef __attribute__((ext_vector_type(4))) short short4v;
typedef __attribute__((ext_vector_type(4))) float f32x4;

// lgkm-only barrier: LDS-coherent workgroup sync WITHOUT draining vmcnt.
#define BAR_LGKM() do { \
    asm volatile("s_waitcnt lgkmcnt(0)" ::: "memory"); \
    __builtin_amdgcn_s_barrier(); \
    __builtin_amdgcn_sched_barrier(0); \
} while (0)

// global -> LDS direct DMA, 16 B/lane. LDS dest must be wave-uniform;
// per-lane GLOBAL source carries the swizzle (pre-swizzled-source pattern).
typedef __attribute__((address_space(3))) short      lds_s;
typedef __attribute__((address_space(1))) const short glb_s;
#define GLD16(g, l) __builtin_amdgcn_global_load_lds((glb_s*)(g), (lds_s*)(l), 16, 0, 0)

__device__ __forceinline__ short bf16b(float f) {
    __hip_bfloat16 h = __float2bfloat16(f);
    short s; __builtin_memcpy(&s, &h, 2);
    return s;
}

__device__ __forceinline__ float bf2f(short s) {
    unsigned int u = ((unsigned int)(unsigned short)s) << 16;
    float f; __builtin_memcpy(&f, &u, 4);
    return f;
}

__device__ __forceinline__ short8 cvt8(float4 a, float4 b) {
    short8 o;
    o[0] = bf16b(a.x); o[1] = bf16b(a.y); o[2] = bf16b(a.z); o[3] = bf16b(a.w);
    o[4] = bf16b(b.x); o[5] = bf16b(b.y); o[6] = bf16b(b.z); o[7] = bf16b(b.w);
    return o;
}

// bf16 LDS tile convention: [row][8 chunks of 8 shorts], chunk c at slot
// c ^ (row & 7). ldfrag(row, c) returns global chunk c (k-offset c*8).
__device__ __forceinline__ short8 ldfrag(const short* __restrict__ lds, int row, int c) {
    return *reinterpret_cast<const short8*>(lds + (((row << 3) + (c ^ (row & 7))) << 3));
}

// ---------------------------------------------------------------------------
// W fp32 [K][N] -> WT bf16 [N][K]  (1024x1024)
// ---------------------------------------------------------------------------
__global__ __launch_bounds__(256)
void tcast(const float* __restrict__ W, short* __restrict__ WT) {
    __shared__ float tile[64][65];
    const int n0 = blockIdx.x << 6, k0 = blockIdx.y << 6;
    const int t = threadIdx.x;
    #pragma unroll
    for (int i = 0; i < 16; ++i) {
        int f = i * 256 + t, r = f >> 6, c = f & 63;
        tile[r][c] = W[(size_t)(k0 + r) * DM + n0 + c];
    }
    __syncthreads();
    #pragma unroll
    for (int i = 0; i < 16; ++i) {
        int f = i * 256 + t, r = f >> 6, c = f & 63;
        WT[(size_t)(n0 + r) * DM + k0 + c] = bf16b(tile[c][r]);
    }
}

// ---------------------------------------------------------------------------
// bf16 MFMA GEMM (FROZEN from round 14): 128x128 tile, BK=64, 4 waves,
// swizzled LDS; B (and bf16-A) staged via global_load_lds w/ pre-swizzled src.
// ---------------------------------------------------------------------------
template<int EPI, int AF32>
__global__ __launch_bounds__(256)
void gemm_nt(const void* __restrict__ Av, const short* __restrict__ BT,
             const float* __restrict__ bias, short* __restrict__ Cb,
             float* __restrict__ Cf) {
    __shared__ __align__(16) short lA[128 * 64];
    __shared__ __align__(16) short lB[128 * 64];
    const int K = 1024;
    const short* A16 = (const short*)Av;
    const float* A32 = (const float*)Av;
    const int id = blockIdx.x;
    const int swz = ((id & 7) << 6) + (id >> 3);   // XCD-aware, 512 % 8 == 0
    const int bm = swz >> 3, bn = swz & 7;
    const int t = threadIdx.x, w = t >> 6, l = t & 63, lg = l >> 4, lr = l & 15;
    const int wm = w >> 1, wn = w & 1;

    const int srow = t >> 1, sw = srow & 7, codd = t & 1;
    const size_t arow = (size_t)(bm * 128 + srow) * K;
    short* la = lA + (srow << 6);

    const int grow = l >> 3;
    const int gcol = ((l & 7) ^ grow) << 3;
    const short* Bg  = BT + (size_t)(bn * 128 + w * 32 + grow) * K + gcol;
    short*       lBw = lB + ((w * 32) << 6);
    const short* Ag  = A16 + (size_t)(bm * 128 + w * 32 + grow) * K + gcol;
    short*       lAw = lA + ((w * 32) << 6);

    f32x4 acc[4][4] = {};
    float4 fa[4][2];
    if (AF32) {
        #pragma unroll
        for (int j = 0; j < 4; ++j) {
            const float* p = A32 + arow + ((codd + (j << 1)) << 3);
            fa[j][0] = *reinterpret_cast<const float4*>(p);
            fa[j][1] = *reinterpret_cast<const float4*>(p + 4);
        }
    }

    for (int k0 = 0; k0 < K; k0 += 64) {
        __syncthreads();
        if (AF32) {
            #pragma unroll
            for (int j = 0; j < 4; ++j) {
                const int c = (codd + (j << 1)) ^ sw;
                *reinterpret_cast<short8*>(la + (c << 3)) = cvt8(fa[j][0], fa[j][1]);
            }
        } else {
            #pragma unroll
            for (int i = 0; i < 4; ++i)
                GLD16(Ag + k0 + (size_t)(i << 3) * K, lAw + (i << 9));
        }
        #pragma unroll
        for (int i = 0; i < 4; ++i)
            GLD16(Bg + k0 + (size_t)(i << 3) * K, lBw + (i << 9));
        __syncthreads();
        if (AF32 && k0 + 64 < K) {
            #pragma unroll
            for (int j = 0; j < 4; ++j) {
                const float* p = A32 + arow + k0 + 64 + ((codd + (j << 1)) << 3);
                fa[j][0] = *reinterpret_cast<const float4*>(p);
                fa[j][1] = *reinterpret_cast<const float4*>(p + 4);
            }
        }
        #pragma unroll
        for (int kk = 0; kk < 2; ++kk) {
            short8 af[4], bfr[4];
            #pragma unroll
            for (int fm = 0; fm < 4; ++fm) af[fm]  = ldfrag(lA, wm * 64 + fm * 16 + lr, kk * 4 + lg);
            #pragma unroll
            for (int fn = 0; fn < 4; ++fn) bfr[fn] = ldfrag(lB, wn * 64 + fn * 16 + lr, kk * 4 + lg);
            #pragma unroll
            for (int fm = 0; fm < 4; ++fm)
                #pragma unroll
                for (int fn = 0; fn < 4; ++fn)
                    acc[fm][fn] = __builtin_amdgcn_mfma_f32_16x16x32_bf16(af[fm], bfr[fn], acc[fm][fn], 0, 0, 0);
        }
    }

    const int rb = bm * 128 + wm * 64 + (lg << 2);
    const int cb = bn * 128 + wn * 64 + lr;
    #pragma unroll
    for (int fm = 0; fm < 4; ++fm) {
        #pragma unroll
        for (int fn = 0; fn < 4; ++fn) {
            const int col = cb + fn * 16;
            if (EPI == 2) {
                const float bv = bias[col];
                #pragma unroll
                for (int r = 0; r < 4; ++r) {
                    const int row = rb + fm * 16 + r;
                    Cf[(size_t)row * DM + col] = acc[fm][fn][r] + bv;
                }
            } else if (EPI == 0) {
                const int h = col >> 6, d = col & 63;
                #pragma unroll
                for (int r = 0; r < 4; ++r) {
                    const int row = rb + fm * 16 + r;
                    const int b = row >> 11, s = row & 2047;
                    Cb[(((size_t)(b * H_ + h) * S_ + s) << 6) + d] = bf16b(acc[fm][fn][r]);
                }
            } else {
                const int h = col >> 6, d = col & 63;
                const int row0 = rb + fm * 16;
                const int b = row0 >> 11, s = row0 & 2047;
                short4v pk;
                #pragma unroll
                for (int r = 0; r < 4; ++r) pk[r] = bf16b(acc[fm][fn][r]);
                *reinterpret_cast<short4v*>(Cb + (((size_t)(b * H_ + h) << 6) + d) * S_ + s) = pk;
            }
        }
    }
}

// ---------------------------------------------------------------------------
// bf16 MFMA causal attention. 128 q-rows/block, 8 waves (16 rows each).
// OCCUPANCY PUSH: lP in bf16 (LDS 48->32 KB) + __launch_bounds__(512,8)
// forcing VGPR<=64 -> target 4 blocks/CU so pass-A compute of one block
// overlaps pass-B store stream of another. attn values = fp32(bf16(p)).
// ---------------------------------------------------------------------------
__global__ __launch_bounds__(512, 8)
void attn_mfma(const short* __restrict__ Qh, const short* __restrict__ Kh,
               const short* __restrict__ VhT, float* __restrict__ attn,
               short* __restrict__ ctxb) {
    __shared__ __align__(16) short smem[128 * 64 + 8 * 16 * 64];  // 32 KB
    short* lQ = smem;               // [128*64] bf16 (staging phase)
    short* lK = smem;               // [64*64]  (aliases lQ; safe)
    short* lV = smem + 64 * 64;
    short* lP = smem + 128 * 64;    // 8 waves x [16][64] bf16

    const int t = threadIdx.x, w = t >> 6, l = t & 63, lg = l >> 4, lr = l & 15;
    // XCD-aware decode: n = xcd + 8*(j + 16*mh); bh = mh*8 + xcd; qt = 15-j.
    const int n   = (int)blockIdx.x;
    const int xcd = n & 7, rest = n >> 3;
    const int j   = rest & 15, mh = rest >> 4;
    const int bh  = (mh << 3) | xcd;
    const int qt  = 15 - j;                // heavy tiles first within each head
    const int q0  = qt << 7;
    const int h   = bh & 15, b = bh >> 4;
    const float SC = 0.18033688f;          // log2(e)/8

    const short* Qg = Qh  + (((size_t)bh * S_ + q0) << 6);
    const short* Kg = Kh  + ((size_t)bh * S_ << 6);
    const short* Vg = VhT + ((size_t)bh << 6) * S_;

    const int wrow = w * 16;
    const int rloc = q0 + wrow + (lg << 2);   // abs q-row of acc reg r=0
    const int wlast = q0 + wrow + 15;         // wave's max q-row
    const int Kw  = wlast >> 6;               // wave's last computed tile
    const int nkb = (q0 + 128) >> 6;          // tiles staged by the block

    // stage Q (128 rows x 8 chunks, 2 chunks/thread)
    {
        const int row = t >> 2, c0 = (t & 3) << 1, sw = row & 7;
        const short* src = Qg + ((size_t)row << 6) + (c0 << 3);
        short8 v0 = *reinterpret_cast<const short8*>(src);
        short8 v1 = *reinterpret_cast<const short8*>(src + 8);
        *reinterpret_cast<short8*>(lQ + (((row << 3) + ((c0    ) ^ sw)) << 3)) = v0;
        *reinterpret_cast<short8*>(lQ + (((row << 3) + ((c0 + 1) ^ sw)) << 3)) = v1;
    }
    __syncthreads();

    const short8 aq0 = ldfrag(lQ, wrow + lr, lg);
    const short8 aq1 = ldfrag(lQ, wrow + lr, lg + 4);

    // staging map for K/V tiles: 512 threads = 64 rows x 8 chunks
    const int srow = t >> 3, sc = t & 7;
    const int sslot = ((srow << 3) + (sc ^ (srow & 7))) << 3;
    const short* Kst = Kg + (srow << 6) + (sc << 3);
    const short* Vst = Vg + (size_t)srow * S_ + (sc << 3);

    // ---------------- pass A: row sums of exp ----------------
    float rsum[4] = {0.f, 0.f, 0.f, 0.f};
    short8 vk = *reinterpret_cast<const short8*>(Kst);       // tile 0
    for (int kb = 0; kb < nkb; ++kb) {
        BAR_LGKM();
        *reinterpret_cast<short8*>(lK + sslot) = vk;
        if (kb + 1 < nkb)
            vk = *reinterpret_cast<const short8*>(Kst + ((size_t)(kb + 1) << 12));
        BAR_LGKM();
        if (kb * 64 > wlast) continue;
        f32x4 acc[4] = {};
        #pragma unroll
        for (int t4 = 0; t4 < 4; ++t4) {
            short8 bk0 = ldfrag(lK, t4 * 16 + lr, lg);
            short8 bk1 = ldfrag(lK, t4 * 16 + lr, lg + 4);
            acc[t4] = __builtin_amdgcn_mfma_f32_16x16x32_bf16(aq0, bk0, acc[t4], 0, 0, 0);
            acc[t4] = __builtin_amdgcn_mfma_f32_16x16x32_bf16(aq1, bk1, acc[t4], 0, 0, 0);
        }
        if (kb * 64 + 63 <= q0 + wrow) {
            #pragma unroll
            for (int t4 = 0; t4 < 4; ++t4)
                #pragma unroll
                for (int r = 0; r < 4; ++r)
                    rsum[r] += exp2f(acc[t4][r] * SC);
        } else {
            #pragma unroll
            for (int t4 = 0; t4 < 4; ++t4) {
                const int cabs = kb * 64 + t4 * 16 + lr;
                #pragma unroll
                for (int r = 0; r < 4; ++r)
                    if (cabs <= rloc + r) rsum[r] += exp2f(acc[t4][r] * SC);
            }
        }
    }
    #pragma unroll
    for (int r = 0; r < 4; ++r) {
        #pragma unroll
        for (int m = 1; m < 16; m <<= 1) rsum[r] += __shfl_xor(rsum[r], m);
        rsum[r] = 1.f / rsum[r];
    }

    // ---------------- pass B: attn write (wide) + PV ----------------
    f32x4 ctxa[4] = {};
    short* lPw = lP + (w << 10);   // this wave's [16][64] bf16 tile
    short8 vv;
    vk = *reinterpret_cast<const short8*>(Kst);
    vv = *reinterpret_cast<const short8*>(Vst);
    for (int kb = 0; kb < nkb; ++kb) {
        BAR_LGKM();
        *reinterpret_cast<short8*>(lK + sslot) = vk;
        *reinterpret_cast<short8*>(lV + sslot) = vv;
        if (kb + 1 < nkb) {
            vk = *reinterpret_cast<const short8*>(Kst + ((size_t)(kb + 1) << 12));
            vv = *reinterpret_cast<const short8*>(Vst + ((kb + 1) << 6));
        }
        BAR_LGKM();
        if (kb * 64 > wlast) continue;
        f32x4 acc[4] = {};
        #pragma unroll
        for (int t4 = 0; t4 < 4; ++t4) {
            short8 bk0 = ldfrag(lK, t4 * 16 + lr, lg);
            short8 bk1 = ldfrag(lK, t4 * 16 + lr, lg + 4);
            acc[t4] = __builtin_amdgcn_mfma_f32_16x16x32_bf16(aq0, bk0, acc[t4], 0, 0, 0);
            acc[t4] = __builtin_amdgcn_mfma_f32_16x16x32_bf16(aq1, bk1, acc[t4], 0, 0, 0);
        }
        const bool fullt = (kb * 64 + 63 <= q0 + wrow);
        // P (bf16) -> wave-private LDS, chunk-8 XOR swizzle (rounds 2-6 layout)
        #pragma unroll
        for (int t4 = 0; t4 < 4; ++t4) {
            const int cl = t4 * 16 + lr;
            const int cabs = kb * 64 + cl;
            #pragma unroll
            for (int r = 0; r < 4; ++r) {
                float p;
                if (!fullt && cabs > rloc + r) p = 0.f;
                else p = exp2f(acc[t4][r] * SC) * rsum[r];
                const int prow = (lg << 2) + r;
                lPw[(prow << 6) + (((t4 * 2 + (lr >> 3)) ^ (prow & 7)) << 3) + (l & 7)] = bf16b(p);
            }
        }
        // wide attn store: read bf16 quads, upconvert, 4x dwordx4 per lane
        {
            float* abase = attn + ((size_t)bh * S_ + q0 + wrow) * S_ + kb * 64;
            const int colc = (l & 15) << 2;
            const int ch0  = (l & 15) >> 1;
            const int half = ((l & 15) & 1) << 2;
            #pragma unroll
            for (int rr = 0; rr < 4; ++rr) {
                const int row = (l >> 4) + (rr << 2);
                short4v p4 = *reinterpret_cast<const short4v*>(
                    lPw + (row << 6) + ((ch0 ^ (row & 7)) << 3) + half);
                f32x4 pv = {bf2f(p4[0]), bf2f(p4[1]), bf2f(p4[2]), bf2f(p4[3])};
                *reinterpret_cast<f32x4*>(abase + (size_t)row * S_ + colc) = pv;
            }
        }
        // PV A-fragments: direct bf16 ldfrag (no conversion)
        short8 pa0 = ldfrag(lPw, lr, lg);
        short8 pa1 = ldfrag(lPw, lr, lg + 4);
        #pragma unroll
        for (int td = 0; td < 4; ++td) {
            short8 v0 = ldfrag(lV, td * 16 + lr, lg);
            short8 v1 = ldfrag(lV, td * 16 + lr, lg + 4);
            ctxa[td] = __builtin_amdgcn_mfma_f32_16x16x32_bf16(pa0, v0, ctxa[td], 0, 0, 0);
            ctxa[td] = __builtin_amdgcn_mfma_f32_16x16x32_bf16(pa1, v1, ctxa[td], 0, 0, 0);
        }
    }

    short* cbase = ctxb + ((size_t)(b * S_) + q0 + wrow + (lg << 2)) * DM + (h << 6);
    #pragma unroll
    for (int td = 0; td < 4; ++td)
        #pragma unroll
        for (int r = 0; r < 4; ++r)
            cbase[(size_t)r * DM + td * 16 + lr] = bf16b(ctxa[td][r]);

    // ---- zero-fill masked tail, wide: 16 lanes cover one row ----
    {
        const f32x4 z = {0.f, 0.f, 0.f, 0.f};
        const int zs = (Kw + 1) << 6;
        const int colc = (l & 15) << 2;
        #pragma unroll
        for (int rr = 0; rr < 4; ++rr) {
            const int row = q0 + wrow + (l >> 4) + (rr << 2);
            float* rowp = attn + ((size_t)bh * S_ + row) * S_;
            for (int c = zs + colc; c < S_; c += 64)
                *reinterpret_cast<f32x4*>(rowp + c) = z;
        }
    }
}

// ---------------------------------------------------------------------------
extern "C" void kernel_launch(void* const* d_in, const int* in_sizes, int n_in,
                              void* d_out, int out_size, void* d_ws, size_t ws_size,
                              hipStream_t stream) {
    const float* q  = (const float*)d_in[0];
    const float* k  = (const float*)d_in[1];
    const float* v  = (const float*)d_in[2];
    // d_in[3]: causal mask, applied analytically
    const float* wq = (const float*)d_in[4];
    const float* wk = (const float*)d_in[5];
    const float* wv = (const float*)d_in[6];
    const float* wd = (const float*)d_in[7];
    const float* bd = (const float*)d_in[8];

    float* out  = (float*)d_out;
    float* attn = (float*)d_out + (size_t)B_ * S_ * DM;

    char* wsc = (char*)d_ws;
    short* ctxb = (short*)wsc;                                   // 16 MB
    short* wT0 = (short*)(wsc + ((size_t)16 << 20));             // 2 MB each
    short* wT1 = (short*)(wsc + ((size_t)18 << 20));
    short* wT2 = (short*)(wsc + ((size_t)20 << 20));
    short* wT3 = (short*)(wsc + ((size_t)22 << 20));
    short* Qh  = (short*)(wsc + ((size_t)24 << 20));             // 16 MB
    short* Kh  = (short*)(wsc + ((size_t)40 << 20));             // 16 MB
    short* VhT = (short*)(wsc + ((size_t)56 << 20));             // 16 MB

    const dim3 b256(256);
    hipLaunchKernelGGL(tcast, dim3(16, 16), b256, 0, stream, wq, wT0);
    hipLaunchKernelGGL(tcast, dim3(16, 16), b256, 0, stream, wk, wT1);
    hipLaunchKernelGGL(tcast, dim3(16, 16), b256, 0, stream, wv, wT2);
    hipLaunchKernelGGL(tcast, dim3(16, 16), b256, 0, stream, wd, wT3);

    hipLaunchKernelGGL((gemm_nt<0, 1>), dim3(512), b256, 0, stream, q, wT0, nullptr, Qh,  nullptr);
    hipLaunchKernelGGL((gemm_nt<0, 1>), dim3(512), b256, 0, stream, k, wT1, nullptr, Kh,  nullptr);
    hipLaunchKernelGGL((gemm_nt<1, 1>), dim3(512), b256, 0, stream, v, wT2, nullptr, VhT, nullptr);

    hipLaunchKernelGGL(attn_mfma, dim3(1024), dim3(512), 0, stream,
                       Qh, Kh, VhT, attn, ctxb);

    hipLaunchKernelGGL((gemm_nt<2, 0>), dim3(512), b256, 0, stream, ctxb, wT3, bd, nullptr, out);
}

// Round 17
// 450.199 us; speedup vs baseline: 1.6682x; 1.6682x over previous
//
#include <hip/hip_runtime.h>
#include <hip/hip_bf16.h>
#include <math.h>

#define B_  4
#define S_  2048
#define DM  1024
#define H_  16

typedef __attribute__((ext_vector_type(8))) short short8;
typedef __attribute__((ext_vector_type(4))) short short4v;
typedef __attribute__((ext_vector_type(4))) float f32x4;

// lgkm-only barrier: LDS-coherent workgroup sync WITHOUT draining vmcnt.
#define BAR_LGKM() do { \
    asm volatile("s_waitcnt lgkmcnt(0)" ::: "memory"); \
    __builtin_amdgcn_s_barrier(); \
    __builtin_amdgcn_sched_barrier(0); \
} while (0)

// Wave-local LDS fence: order cross-lane ds_write -> ds_read within a wave.
// "memory" clobber + sched_barrier(0) stop the compiler from hoisting the
// reads above the writes (they are cross-thread at language level — the
// round-16 failure was exactly this reorder); lgkmcnt(0) waits HW completion.
#define WAVE_FENCE() do { \
    asm volatile("s_waitcnt lgkmcnt(0)" ::: "memory"); \
    __builtin_amdgcn_sched_barrier(0); \
} while (0)

// global -> LDS direct DMA, 16 B/lane. LDS dest must be wave-uniform;
// per-lane GLOBAL source carries the swizzle (pre-swizzled-source pattern).
typedef __attribute__((address_space(3))) short      lds_s;
typedef __attribute__((address_space(1))) const short glb_s;
#define GLD16(g, l) __builtin_amdgcn_global_load_lds((glb_s*)(g), (lds_s*)(l), 16, 0, 0)

__device__ __forceinline__ short bf16b(float f) {
    __hip_bfloat16 h = __float2bfloat16(f);
    short s; __builtin_memcpy(&s, &h, 2);
    return s;
}

__device__ __forceinline__ float bf2f(short s) {
    unsigned int u = ((unsigned int)(unsigned short)s) << 16;
    float f; __builtin_memcpy(&f, &u, 4);
    return f;
}

__device__ __forceinline__ short8 cvt8(float4 a, float4 b) {
    short8 o;
    o[0] = bf16b(a.x); o[1] = bf16b(a.y); o[2] = bf16b(a.z); o[3] = bf16b(a.w);
    o[4] = bf16b(b.x); o[5] = bf16b(b.y); o[6] = bf16b(b.z); o[7] = bf16b(b.w);
    return o;
}

// bf16 LDS tile convention: [row][8 chunks of 8 shorts], chunk c at slot
// c ^ (row & 7). ldfrag(row, c) returns global chunk c (k-offset c*8).
__device__ __forceinline__ short8 ldfrag(const short* __restrict__ lds, int row, int c) {
    return *reinterpret_cast<const short8*>(lds + (((row << 3) + (c ^ (row & 7))) << 3));
}

// ---------------------------------------------------------------------------
// W fp32 [K][N] -> WT bf16 [N][K]  (1024x1024)
// ---------------------------------------------------------------------------
__global__ __launch_bounds__(256)
void tcast(const float* __restrict__ W, short* __restrict__ WT) {
    __shared__ float tile[64][65];
    const int n0 = blockIdx.x << 6, k0 = blockIdx.y << 6;
    const int t = threadIdx.x;
    #pragma unroll
    for (int i = 0; i < 16; ++i) {
        int f = i * 256 + t, r = f >> 6, c = f & 63;
        tile[r][c] = W[(size_t)(k0 + r) * DM + n0 + c];
    }
    __syncthreads();
    #pragma unroll
    for (int i = 0; i < 16; ++i) {
        int f = i * 256 + t, r = f >> 6, c = f & 63;
        WT[(size_t)(n0 + r) * DM + k0 + c] = bf16b(tile[c][r]);
    }
}

// ---------------------------------------------------------------------------
// bf16 MFMA GEMM (FROZEN from round 14): 128x128 tile, BK=64, 4 waves,
// swizzled LDS; B (and bf16-A) staged via global_load_lds w/ pre-swizzled src.
// ---------------------------------------------------------------------------
template<int EPI, int AF32>
__global__ __launch_bounds__(256)
void gemm_nt(const void* __restrict__ Av, const short* __restrict__ BT,
             const float* __restrict__ bias, short* __restrict__ Cb,
             float* __restrict__ Cf) {
    __shared__ __align__(16) short lA[128 * 64];
    __shared__ __align__(16) short lB[128 * 64];
    const int K = 1024;
    const short* A16 = (const short*)Av;
    const float* A32 = (const float*)Av;
    const int id = blockIdx.x;
    const int swz = ((id & 7) << 6) + (id >> 3);   // XCD-aware, 512 % 8 == 0
    const int bm = swz >> 3, bn = swz & 7;
    const int t = threadIdx.x, w = t >> 6, l = t & 63, lg = l >> 4, lr = l & 15;
    const int wm = w >> 1, wn = w & 1;

    const int srow = t >> 1, sw = srow & 7, codd = t & 1;
    const size_t arow = (size_t)(bm * 128 + srow) * K;
    short* la = lA + (srow << 6);

    const int grow = l >> 3;
    const int gcol = ((l & 7) ^ grow) << 3;
    const short* Bg  = BT + (size_t)(bn * 128 + w * 32 + grow) * K + gcol;
    short*       lBw = lB + ((w * 32) << 6);
    const short* Ag  = A16 + (size_t)(bm * 128 + w * 32 + grow) * K + gcol;
    short*       lAw = lA + ((w * 32) << 6);

    f32x4 acc[4][4] = {};
    float4 fa[4][2];
    if (AF32) {
        #pragma unroll
        for (int j = 0; j < 4; ++j) {
            const float* p = A32 + arow + ((codd + (j << 1)) << 3);
            fa[j][0] = *reinterpret_cast<const float4*>(p);
            fa[j][1] = *reinterpret_cast<const float4*>(p + 4);
        }
    }

    for (int k0 = 0; k0 < K; k0 += 64) {
        __syncthreads();
        if (AF32) {
            #pragma unroll
            for (int j = 0; j < 4; ++j) {
                const int c = (codd + (j << 1)) ^ sw;
                *reinterpret_cast<short8*>(la + (c << 3)) = cvt8(fa[j][0], fa[j][1]);
            }
        } else {
            #pragma unroll
            for (int i = 0; i < 4; ++i)
                GLD16(Ag + k0 + (size_t)(i << 3) * K, lAw + (i << 9));
        }
        #pragma unroll
        for (int i = 0; i < 4; ++i)
            GLD16(Bg + k0 + (size_t)(i << 3) * K, lBw + (i << 9));
        __syncthreads();
        if (AF32 && k0 + 64 < K) {
            #pragma unroll
            for (int j = 0; j < 4; ++j) {
                const float* p = A32 + arow + k0 + 64 + ((codd + (j << 1)) << 3);
                fa[j][0] = *reinterpret_cast<const float4*>(p);
                fa[j][1] = *reinterpret_cast<const float4*>(p + 4);
            }
        }
        #pragma unroll
        for (int kk = 0; kk < 2; ++kk) {
            short8 af[4], bfr[4];
            #pragma unroll
            for (int fm = 0; fm < 4; ++fm) af[fm]  = ldfrag(lA, wm * 64 + fm * 16 + lr, kk * 4 + lg);
            #pragma unroll
            for (int fn = 0; fn < 4; ++fn) bfr[fn] = ldfrag(lB, wn * 64 + fn * 16 + lr, kk * 4 + lg);
            #pragma unroll
            for (int fm = 0; fm < 4; ++fm)
                #pragma unroll
                for (int fn = 0; fn < 4; ++fn)
                    acc[fm][fn] = __builtin_amdgcn_mfma_f32_16x16x32_bf16(af[fm], bfr[fn], acc[fm][fn], 0, 0, 0);
        }
    }

    const int rb = bm * 128 + wm * 64 + (lg << 2);
    const int cb = bn * 128 + wn * 64 + lr;
    #pragma unroll
    for (int fm = 0; fm < 4; ++fm) {
        #pragma unroll
        for (int fn = 0; fn < 4; ++fn) {
            const int col = cb + fn * 16;
            if (EPI == 2) {
                const float bv = bias[col];
                #pragma unroll
                for (int r = 0; r < 4; ++r) {
                    const int row = rb + fm * 16 + r;
                    Cf[(size_t)row * DM + col] = acc[fm][fn][r] + bv;
                }
            } else if (EPI == 0) {
                const int h = col >> 6, d = col & 63;
                #pragma unroll
                for (int r = 0; r < 4; ++r) {
                    const int row = rb + fm * 16 + r;
                    const int b = row >> 11, s = row & 2047;
                    Cb[(((size_t)(b * H_ + h) * S_ + s) << 6) + d] = bf16b(acc[fm][fn][r]);
                }
            } else {
                const int h = col >> 6, d = col & 63;
                const int row0 = rb + fm * 16;
                const int b = row0 >> 11, s = row0 & 2047;
                short4v pk;
                #pragma unroll
                for (int r = 0; r < 4; ++r) pk[r] = bf16b(acc[fm][fn][r]);
                *reinterpret_cast<short4v*>(Cb + (((size_t)(b * H_ + h) << 6) + d) * S_ + s) = pk;
            }
        }
    }
}

// ---------------------------------------------------------------------------
// bf16 MFMA causal attention. 128 q-rows/block, 8 waves (16 rows each).
// (512,4) natural bounds + bf16 lP (32 KB LDS) + WAVE_FENCE between the
// cross-lane lPw writes and reads (fixes the round-16 compiler-reorder race).
// ---------------------------------------------------------------------------
__global__ __launch_bounds__(512, 4)
void attn_mfma(const short* __restrict__ Qh, const short* __restrict__ Kh,
               const short* __restrict__ VhT, float* __restrict__ attn,
               short* __restrict__ ctxb) {
    __shared__ __align__(16) short smem[128 * 64 + 8 * 16 * 64];  // 32 KB
    short* lQ = smem;               // [128*64] bf16 (staging phase)
    short* lK = smem;               // [64*64]  (aliases lQ; safe)
    short* lV = smem + 64 * 64;
    short* lP = smem + 128 * 64;    // 8 waves x [16][64] bf16

    const int t = threadIdx.x, w = t >> 6, l = t & 63, lg = l >> 4, lr = l & 15;
    // XCD-aware decode: n = xcd + 8*(j + 16*mh); bh = mh*8 + xcd; qt = 15-j.
    const int n   = (int)blockIdx.x;
    const int xcd = n & 7, rest = n >> 3;
    const int j   = rest & 15, mh = rest >> 4;
    const int bh  = (mh << 3) | xcd;
    const int qt  = 15 - j;                // heavy tiles first within each head
    const int q0  = qt << 7;
    const int h   = bh & 15, b = bh >> 4;
    const float SC = 0.18033688f;          // log2(e)/8

    const short* Qg = Qh  + (((size_t)bh * S_ + q0) << 6);
    const short* Kg = Kh  + ((size_t)bh * S_ << 6);
    const short* Vg = VhT + ((size_t)bh << 6) * S_;

    const int wrow = w * 16;
    const int rloc = q0 + wrow + (lg << 2);   // abs q-row of acc reg r=0
    const int wlast = q0 + wrow + 15;         // wave's max q-row
    const int Kw  = wlast >> 6;               // wave's last computed tile
    const int nkb = (q0 + 128) >> 6;          // tiles staged by the block

    // stage Q (128 rows x 8 chunks, 2 chunks/thread)
    {
        const int row = t >> 2, c0 = (t & 3) << 1, sw = row & 7;
        const short* src = Qg + ((size_t)row << 6) + (c0 << 3);
        short8 v0 = *reinterpret_cast<const short8*>(src);
        short8 v1 = *reinterpret_cast<const short8*>(src + 8);
        *reinterpret_cast<short8*>(lQ + (((row << 3) + ((c0    ) ^ sw)) << 3)) = v0;
        *reinterpret_cast<short8*>(lQ + (((row << 3) + ((c0 + 1) ^ sw)) << 3)) = v1;
    }
    __syncthreads();

    const short8 aq0 = ldfrag(lQ, wrow + lr, lg);
    const short8 aq1 = ldfrag(lQ, wrow + lr, lg + 4);

    // staging map for K/V tiles: 512 threads = 64 rows x 8 chunks
    const int srow = t >> 3, sc = t & 7;
    const int sslot = ((srow << 3) + (sc ^ (srow & 7))) << 3;
    const short* Kst = Kg + (srow << 6) + (sc << 3);
    const short* Vst = Vg + (size_t)srow * S_ + (sc << 3);

    // ---------------- pass A: row sums of exp ----------------
    float rsum[4] = {0.f, 0.f, 0.f, 0.f};
    short8 vk = *reinterpret_cast<const short8*>(Kst);       // tile 0
    for (int kb = 0; kb < nkb; ++kb) {
        BAR_LGKM();
        *reinterpret_cast<short8*>(lK + sslot) = vk;
        if (kb + 1 < nkb)
            vk = *reinterpret_cast<const short8*>(Kst + ((size_t)(kb + 1) << 12));
        BAR_LGKM();
        if (kb * 64 > wlast) continue;
        f32x4 acc[4] = {};
        #pragma unroll
        for (int t4 = 0; t4 < 4; ++t4) {
            short8 bk0 = ldfrag(lK, t4 * 16 + lr, lg);
            short8 bk1 = ldfrag(lK, t4 * 16 + lr, lg + 4);
            acc[t4] = __builtin_amdgcn_mfma_f32_16x16x32_bf16(aq0, bk0, acc[t4], 0, 0, 0);
            acc[t4] = __builtin_amdgcn_mfma_f32_16x16x32_bf16(aq1, bk1, acc[t4], 0, 0, 0);
        }
        if (kb * 64 + 63 <= q0 + wrow) {
            #pragma unroll
            for (int t4 = 0; t4 < 4; ++t4)
                #pragma unroll
                for (int r = 0; r < 4; ++r)
                    rsum[r] += exp2f(acc[t4][r] * SC);
        } else {
            #pragma unroll
            for (int t4 = 0; t4 < 4; ++t4) {
                const int cabs = kb * 64 + t4 * 16 + lr;
                #pragma unroll
                for (int r = 0; r < 4; ++r)
                    if (cabs <= rloc + r) rsum[r] += exp2f(acc[t4][r] * SC);
            }
        }
    }
    #pragma unroll
    for (int r = 0; r < 4; ++r) {
        #pragma unroll
        for (int m = 1; m < 16; m <<= 1) rsum[r] += __shfl_xor(rsum[r], m);
        rsum[r] = 1.f / rsum[r];
    }

    // ---------------- pass B: attn write (wide) + PV ----------------
    f32x4 ctxa[4] = {};
    short* lPw = lP + (w << 10);   // this wave's [16][64] bf16 tile
    short8 vv;
    vk = *reinterpret_cast<const short8*>(Kst);
    vv = *reinterpret_cast<const short8*>(Vst);
    for (int kb = 0; kb < nkb; ++kb) {
        BAR_LGKM();
        *reinterpret_cast<short8*>(lK + sslot) = vk;
        *reinterpret_cast<short8*>(lV + sslot) = vv;
        if (kb + 1 < nkb) {
            vk = *reinterpret_cast<const short8*>(Kst + ((size_t)(kb + 1) << 12));
            vv = *reinterpret_cast<const short8*>(Vst + ((kb + 1) << 6));
        }
        BAR_LGKM();
        if (kb * 64 > wlast) continue;
        f32x4 acc[4] = {};
        #pragma unroll
        for (int t4 = 0; t4 < 4; ++t4) {
            short8 bk0 = ldfrag(lK, t4 * 16 + lr, lg);
            short8 bk1 = ldfrag(lK, t4 * 16 + lr, lg + 4);
            acc[t4] = __builtin_amdgcn_mfma_f32_16x16x32_bf16(aq0, bk0, acc[t4], 0, 0, 0);
            acc[t4] = __builtin_amdgcn_mfma_f32_16x16x32_bf16(aq1, bk1, acc[t4], 0, 0, 0);
        }
        const bool fullt = (kb * 64 + 63 <= q0 + wrow);
        // P (bf16) -> wave-private LDS, chunk-8 XOR swizzle (rounds 2-6 layout)
        #pragma unroll
        for (int t4 = 0; t4 < 4; ++t4) {
            const int cl = t4 * 16 + lr;
            const int cabs = kb * 64 + cl;
            #pragma unroll
            for (int r = 0; r < 4; ++r) {
                float p;
                if (!fullt && cabs > rloc + r) p = 0.f;
                else p = exp2f(acc[t4][r] * SC) * rsum[r];
                const int prow = (lg << 2) + r;
                lPw[(prow << 6) + (((t4 * 2 + (lr >> 3)) ^ (prow & 7)) << 3) + (l & 7)] = bf16b(p);
            }
        }
        WAVE_FENCE();   // cross-lane lPw RAW: writes above, reads below
        // wide attn store: read bf16 quads, upconvert, 4x dwordx4 per lane
        {
            float* abase = attn + ((size_t)bh * S_ + q0 + wrow) * S_ + kb * 64;
            const int colc = (l & 15) << 2;
            const int ch0  = (l & 15) >> 1;
            const int half = ((l & 15) & 1) << 2;
            #pragma unroll
            for (int rr = 0; rr < 4; ++rr) {
                const int row = (l >> 4) + (rr << 2);
                short4v p4 = *reinterpret_cast<const short4v*>(
                    lPw + (row << 6) + ((ch0 ^ (row & 7)) << 3) + half);
                f32x4 pv = {bf2f(p4[0]), bf2f(p4[1]), bf2f(p4[2]), bf2f(p4[3])};
                *reinterpret_cast<f32x4*>(abase + (size_t)row * S_ + colc) = pv;
            }
        }
        // PV A-fragments: direct bf16 ldfrag (no conversion)
        short8 pa0 = ldfrag(lPw, lr, lg);
        short8 pa1 = ldfrag(lPw, lr, lg + 4);
        #pragma unroll
        for (int td = 0; td < 4; ++td) {
            short8 v0 = ldfrag(lV, td * 16 + lr, lg);
            short8 v1 = ldfrag(lV, td * 16 + lr, lg + 4);
            ctxa[td] = __builtin_amdgcn_mfma_f32_16x16x32_bf16(pa0, v0, ctxa[td], 0, 0, 0);
            ctxa[td] = __builtin_amdgcn_mfma_f32_16x16x32_bf16(pa1, v1, ctxa[td], 0, 0, 0);
        }
    }

    short* cbase = ctxb + ((size_t)(b * S_) + q0 + wrow + (lg << 2)) * DM + (h << 6);
    #pragma unroll
    for (int td = 0; td < 4; ++td)
        #pragma unroll
        for (int r = 0; r < 4; ++r)
            cbase[(size_t)r * DM + td * 16 + lr] = bf16b(ctxa[td][r]);

    // ---- zero-fill masked tail, wide: 16 lanes cover one row ----
    {
        const f32x4 z = {0.f, 0.f, 0.f, 0.f};
        const int zs = (Kw + 1) << 6;
        const int colc = (l & 15) << 2;
        #pragma unroll
        for (int rr = 0; rr < 4; ++rr) {
            const int row = q0 + wrow + (l >> 4) + (rr << 2);
            float* rowp = attn + ((size_t)bh * S_ + row) * S_;
            for (int c = zs + colc; c < S_; c += 64)
                *reinterpret_cast<f32x4*>(rowp + c) = z;
        }
    }
}

// ---------------------------------------------------------------------------
extern "C" void kernel_launch(void* const* d_in, const int* in_sizes, int n_in,
                              void* d_out, int out_size, void* d_ws, size_t ws_size,
                              hipStream_t stream) {
    const float* q  = (const float*)d_in[0];
    const float* k  = (const float*)d_in[1];
    const float* v  = (const float*)d_in[2];
    // d_in[3]: causal mask, applied analytically
    const float* wq = (const float*)d_in[4];
    const float* wk = (const float*)d_in[5];
    const float* wv = (const float*)d_in[6];
    const float* wd = (const float*)d_in[7];
    const float* bd = (const float*)d_in[8];

    float* out  = (float*)d_out;
    float* attn = (float*)d_out + (size_t)B_ * S_ * DM;

    char* wsc = (char*)d_ws;
    short* ctxb = (short*)wsc;                                   // 16 MB
    short* wT0 = (short*)(wsc + ((size_t)16 << 20));             // 2 MB each
    short* wT1 = (short*)(wsc + ((size_t)18 << 20));
    short* wT2 = (short*)(wsc + ((size_t)20 << 20));
    short* wT3 = (short*)(wsc + ((size_t)22 << 20));
    short* Qh  = (short*)(wsc + ((size_t)24 << 20));             // 16 MB
    short* Kh  = (short*)(wsc + ((size_t)40 << 20));             // 16 MB
    short* VhT = (short*)(wsc + ((size_t)56 << 20));             // 16 MB

    const dim3 b256(256);
    hipLaunchKernelGGL(tcast, dim3(16, 16), b256, 0, stream, wq, wT0);
    hipLaunchKernelGGL(tcast, dim3(16, 16), b256, 0, stream, wk, wT1);
    hipLaunchKernelGGL(tcast, dim3(16, 16), b256, 0, stream, wv, wT2);
    hipLaunchKernelGGL(tcast, dim3(16, 16), b256, 0, stream, wd, wT3);

    hipLaunchKernelGGL((gemm_nt<0, 1>), dim3(512), b256, 0, stream, q, wT0, nullptr, Qh,  nullptr);
    hipLaunchKernelGGL((gemm_nt<0, 1>), dim3(512), b256, 0, stream, k, wT1, nullptr, Kh,  nullptr);
    hipLaunchKernelGGL((gemm_nt<1, 1>), dim3(512), b256, 0, stream, v, wT2, nullptr, VhT, nullptr);

    hipLaunchKernelGGL(attn_mfma, dim3(1024), dim3(512), 0, stream,
                       Qh, Kh, VhT, attn, ctxb);

    hipLaunchKernelGGL((gemm_nt<2, 0>), dim3(512), b256, 0, stream, ctxb, wT3, bd, nullptr, out);
}

// Round 18
// 441.570 us; speedup vs baseline: 1.7008x; 1.0195x over previous
//
#include <hip/hip_runtime.h>
#include <hip/hip_bf16.h>
#include <math.h>

#define B_  4
#define S_  2048
#define DM  1024
#define H_  16

typedef __attribute__((ext_vector_type(8))) short short8;
typedef __attribute__((ext_vector_type(4))) short short4v;
typedef __attribute__((ext_vector_type(4))) float f32x4;

// lgkm-only barrier: LDS-coherent workgroup sync WITHOUT draining vmcnt.
#define BAR_LGKM() do { \
    asm volatile("s_waitcnt lgkmcnt(0)" ::: "memory"); \
    __builtin_amdgcn_s_barrier(); \
    __builtin_amdgcn_sched_barrier(0); \
} while (0)

// Wave-local LDS fence: order cross-lane ds_write -> ds_read within a wave.
#define WAVE_FENCE() do { \
    asm volatile("s_waitcnt lgkmcnt(0)" ::: "memory"); \
    __builtin_amdgcn_sched_barrier(0); \
} while (0)

// global -> LDS direct DMA, 16 B/lane (pre-swizzled-source pattern).
typedef __attribute__((address_space(3))) short      lds_s;
typedef __attribute__((address_space(1))) const short glb_s;
#define GLD16(g, l) __builtin_amdgcn_global_load_lds((glb_s*)(g), (lds_s*)(l), 16, 0, 0)

__device__ __forceinline__ short bf16b(float f) {
    __hip_bfloat16 h = __float2bfloat16(f);
    short s; __builtin_memcpy(&s, &h, 2);
    return s;
}

__device__ __forceinline__ float bf2f(short s) {
    unsigned int u = ((unsigned int)(unsigned short)s) << 16;
    float f; __builtin_memcpy(&f, &u, 4);
    return f;
}

__device__ __forceinline__ short8 cvt8(float4 a, float4 b) {
    short8 o;
    o[0] = bf16b(a.x); o[1] = bf16b(a.y); o[2] = bf16b(a.z); o[3] = bf16b(a.w);
    o[4] = bf16b(b.x); o[5] = bf16b(b.y); o[6] = bf16b(b.z); o[7] = bf16b(b.w);
    return o;
}

// bf16 LDS tile convention: [row][8 chunks of 8 shorts], chunk c at slot
// c ^ (row & 7). ldfrag(row, c) returns global chunk c (k-offset c*8).
__device__ __forceinline__ short8 ldfrag(const short* __restrict__ lds, int row, int c) {
    return *reinterpret_cast<const short8*>(lds + (((row << 3) + (c ^ (row & 7))) << 3));
}

// ---------------------------------------------------------------------------
// W fp32 [K][N] -> WT bf16 [N][K]  (1024x1024)
// ---------------------------------------------------------------------------
__global__ __launch_bounds__(256)
void tcast(const float* __restrict__ W, short* __restrict__ WT) {
    __shared__ float tile[64][65];
    const int n0 = blockIdx.x << 6, k0 = blockIdx.y << 6;
    const int t = threadIdx.x;
    #pragma unroll
    for (int i = 0; i < 16; ++i) {
        int f = i * 256 + t, r = f >> 6, c = f & 63;
        tile[r][c] = W[(size_t)(k0 + r) * DM + n0 + c];
    }
    __syncthreads();
    #pragma unroll
    for (int i = 0; i < 16; ++i) {
        int f = i * 256 + t, r = f >> 6, c = f & 63;
        WT[(size_t)(n0 + r) * DM + k0 + c] = bf16b(tile[c][r]);
    }
}

// ---------------------------------------------------------------------------
// bf16 MFMA GEMM (FROZEN from round 14): 128x128 tile, BK=64, 4 waves,
// swizzled LDS; B (and bf16-A) staged via global_load_lds w/ pre-swizzled src.
// ---------------------------------------------------------------------------
template<int EPI, int AF32>
__global__ __launch_bounds__(256)
void gemm_nt(const void* __restrict__ Av, const short* __restrict__ BT,
             const float* __restrict__ bias, short* __restrict__ Cb,
             float* __restrict__ Cf) {
    __shared__ __align__(16) short lA[128 * 64];
    __shared__ __align__(16) short lB[128 * 64];
    const int K = 1024;
    const short* A16 = (const short*)Av;
    const float* A32 = (const float*)Av;
    const int id = blockIdx.x;
    const int swz = ((id & 7) << 6) + (id >> 3);   // XCD-aware, 512 % 8 == 0
    const int bm = swz >> 3, bn = swz & 7;
    const int t = threadIdx.x, w = t >> 6, l = t & 63, lg = l >> 4, lr = l & 15;
    const int wm = w >> 1, wn = w & 1;

    const int srow = t >> 1, sw = srow & 7, codd = t & 1;
    const size_t arow = (size_t)(bm * 128 + srow) * K;
    short* la = lA + (srow << 6);

    const int grow = l >> 3;
    const int gcol = ((l & 7) ^ grow) << 3;
    const short* Bg  = BT + (size_t)(bn * 128 + w * 32 + grow) * K + gcol;
    short*       lBw = lB + ((w * 32) << 6);
    const short* Ag  = A16 + (size_t)(bm * 128 + w * 32 + grow) * K + gcol;
    short*       lAw = lA + ((w * 32) << 6);

    f32x4 acc[4][4] = {};
    float4 fa[4][2];
    if (AF32) {
        #pragma unroll
        for (int j = 0; j < 4; ++j) {
            const float* p = A32 + arow + ((codd + (j << 1)) << 3);
            fa[j][0] = *reinterpret_cast<const float4*>(p);
            fa[j][1] = *reinterpret_cast<const float4*>(p + 4);
        }
    }

    for (int k0 = 0; k0 < K; k0 += 64) {
        __syncthreads();
        if (AF32) {
            #pragma unroll
            for (int j = 0; j < 4; ++j) {
                const int c = (codd + (j << 1)) ^ sw;
                *reinterpret_cast<short8*>(la + (c << 3)) = cvt8(fa[j][0], fa[j][1]);
            }
        } else {
            #pragma unroll
            for (int i = 0; i < 4; ++i)
                GLD16(Ag + k0 + (size_t)(i << 3) * K, lAw + (i << 9));
        }
        #pragma unroll
        for (int i = 0; i < 4; ++i)
            GLD16(Bg + k0 + (size_t)(i << 3) * K, lBw + (i << 9));
        __syncthreads();
        if (AF32 && k0 + 64 < K) {
            #pragma unroll
            for (int j = 0; j < 4; ++j) {
                const float* p = A32 + arow + k0 + 64 + ((codd + (j << 1)) << 3);
                fa[j][0] = *reinterpret_cast<const float4*>(p);
                fa[j][1] = *reinterpret_cast<const float4*>(p + 4);
            }
        }
        #pragma unroll
        for (int kk = 0; kk < 2; ++kk) {
            short8 af[4], bfr[4];
            #pragma unroll
            for (int fm = 0; fm < 4; ++fm) af[fm]  = ldfrag(lA, wm * 64 + fm * 16 + lr, kk * 4 + lg);
            #pragma unroll
            for (int fn = 0; fn < 4; ++fn) bfr[fn] = ldfrag(lB, wn * 64 + fn * 16 + lr, kk * 4 + lg);
            #pragma unroll
            for (int fm = 0; fm < 4; ++fm)
                #pragma unroll
                for (int fn = 0; fn < 4; ++fn)
                    acc[fm][fn] = __builtin_amdgcn_mfma_f32_16x16x32_bf16(af[fm], bfr[fn], acc[fm][fn], 0, 0, 0);
        }
    }

    const int rb = bm * 128 + wm * 64 + (lg << 2);
    const int cb = bn * 128 + wn * 64 + lr;
    #pragma unroll
    for (int fm = 0; fm < 4; ++fm) {
        #pragma unroll
        for (int fn = 0; fn < 4; ++fn) {
            const int col = cb + fn * 16;
            if (EPI == 2) {
                const float bv = bias[col];
                #pragma unroll
                for (int r = 0; r < 4; ++r) {
                    const int row = rb + fm * 16 + r;
                    Cf[(size_t)row * DM + col] = acc[fm][fn][r] + bv;
                }
            } else if (EPI == 0) {
                const int h = col >> 6, d = col & 63;
                #pragma unroll
                for (int r = 0; r < 4; ++r) {
                    const int row = rb + fm * 16 + r;
                    const int b = row >> 11, s = row & 2047;
                    Cb[(((size_t)(b * H_ + h) * S_ + s) << 6) + d] = bf16b(acc[fm][fn][r]);
                }
            } else {
                const int h = col >> 6, d = col & 63;
                const int row0 = rb + fm * 16;
                const int b = row0 >> 11, s = row0 & 2047;
                short4v pk;
                #pragma unroll
                for (int r = 0; r < 4; ++r) pk[r] = bf16b(acc[fm][fn][r]);
                *reinterpret_cast<short4v*>(Cb + (((size_t)(b * H_ + h) << 6) + d) * S_ + s) = pk;
            }
        }
    }
}

// ---------------------------------------------------------------------------
// bf16 MFMA causal attention — 64 q-rows/block, 4 waves (16 rows each),
// 256 threads. Smaller independent blocks -> 4 blocks/CU (vs 2) so pass-A
// compute of some blocks overlaps pass-B store streams of others (raises
// attn-store duty cycle). Inner code identical to round 17 (WAVE_FENCE kept).
// LDS 24 KB: lK(8K, aliases lQ) + lV(8K) + lP 4x2K.
// ---------------------------------------------------------------------------
__global__ __launch_bounds__(256, 4)
void attn_mfma(const short* __restrict__ Qh, const short* __restrict__ Kh,
               const short* __restrict__ VhT, float* __restrict__ attn,
               short* __restrict__ ctxb) {
    __shared__ __align__(16) short smem[64 * 64 * 2 + 4 * 16 * 64];  // 24 KB
    short* lQ = smem;               // [64*64] bf16 (staging phase, aliases lK)
    short* lK = smem;
    short* lV = smem + 64 * 64;
    short* lP = smem + 64 * 64 * 2; // 4 waves x [16][64] bf16

    const int t = threadIdx.x, w = t >> 6, l = t & 63, lg = l >> 4, lr = l & 15;
    // XCD decode: n = xcd + 8*(j + 32*mh); bh = mh*8 + xcd; qt = 31-j.
    const int n   = (int)blockIdx.x;
    const int xcd = n & 7, rest = n >> 3;
    const int j   = rest & 31, mh = rest >> 5;
    const int bh  = (mh << 3) | xcd;
    const int qt  = 31 - j;                // heavy tiles first within each head
    const int q0  = qt << 6;
    const int h   = bh & 15, b = bh >> 4;
    const float SC = 0.18033688f;          // log2(e)/8

    const short* Qg = Qh  + (((size_t)bh * S_ + q0) << 6);
    const short* Kg = Kh  + ((size_t)bh * S_ << 6);
    const short* Vg = VhT + ((size_t)bh << 6) * S_;

    const int wrow = w * 16;
    const int rloc = q0 + wrow + (lg << 2);   // abs q-row of acc reg r=0
    const int nkb = qt + 1;                   // tiles 0..qt (all waves active)

    // staging map (Q/K/V): 256 threads = 64 rows x 2 chunk-pairs
    const int srow = t >> 2, sc0 = (t & 3) << 1, ssw = srow & 7;
    const int sslot0 = ((srow << 3) + ((sc0    ) ^ ssw)) << 3;
    const int sslot1 = ((srow << 3) + ((sc0 + 1) ^ ssw)) << 3;
    const short* Kst = Kg + (srow << 6) + (sc0 << 3);
    const short* Vst = Vg + (size_t)srow * S_ + (sc0 << 3);

    // stage Q (64 rows x 8 chunks, 2 chunks/thread) into lQ (aliases lK)
    {
        const short* src = Qg + (srow << 6) + (sc0 << 3);
        short8 v0 = *reinterpret_cast<const short8*>(src);
        short8 v1 = *reinterpret_cast<const short8*>(src + 8);
        *reinterpret_cast<short8*>(lQ + sslot0) = v0;
        *reinterpret_cast<short8*>(lQ + sslot1) = v1;
    }
    __syncthreads();

    const short8 aq0 = ldfrag(lQ, wrow + lr, lg);
    const short8 aq1 = ldfrag(lQ, wrow + lr, lg + 4);

    // ---------------- pass A: row sums of exp ----------------
    float rsum[4] = {0.f, 0.f, 0.f, 0.f};
    short8 vk0 = *reinterpret_cast<const short8*>(Kst);
    short8 vk1 = *reinterpret_cast<const short8*>(Kst + 8);
    for (int kb = 0; kb < nkb; ++kb) {
        BAR_LGKM();   // waits prior ds_reads (incl. Q frags at kb=0)
        *reinterpret_cast<short8*>(lK + sslot0) = vk0;
        *reinterpret_cast<short8*>(lK + sslot1) = vk1;
        if (kb + 1 < nkb) {
            vk0 = *reinterpret_cast<const short8*>(Kst + ((size_t)(kb + 1) << 12));
            vk1 = *reinterpret_cast<const short8*>(Kst + ((size_t)(kb + 1) << 12) + 8);
        }
        BAR_LGKM();
        f32x4 acc[4] = {};
        #pragma unroll
        for (int t4 = 0; t4 < 4; ++t4) {
            short8 bk0 = ldfrag(lK, t4 * 16 + lr, lg);
            short8 bk1 = ldfrag(lK, t4 * 16 + lr, lg + 4);
            acc[t4] = __builtin_amdgcn_mfma_f32_16x16x32_bf16(aq0, bk0, acc[t4], 0, 0, 0);
            acc[t4] = __builtin_amdgcn_mfma_f32_16x16x32_bf16(aq1, bk1, acc[t4], 0, 0, 0);
        }
        if (kb < qt) {
            #pragma unroll
            for (int t4 = 0; t4 < 4; ++t4)
                #pragma unroll
                for (int r = 0; r < 4; ++r)
                    rsum[r] += exp2f(acc[t4][r] * SC);
        } else {
            #pragma unroll
            for (int t4 = 0; t4 < 4; ++t4) {
                const int cabs = kb * 64 + t4 * 16 + lr;
                #pragma unroll
                for (int r = 0; r < 4; ++r)
                    if (cabs <= rloc + r) rsum[r] += exp2f(acc[t4][r] * SC);
            }
        }
    }
    #pragma unroll
    for (int r = 0; r < 4; ++r) {
        #pragma unroll
        for (int m = 1; m < 16; m <<= 1) rsum[r] += __shfl_xor(rsum[r], m);
        rsum[r] = 1.f / rsum[r];
    }

    // ---------------- pass B: attn write (wide) + PV ----------------
    f32x4 ctxa[4] = {};
    short* lPw = lP + (w << 10);   // this wave's [16][64] bf16 tile
    short8 vv0, vv1;
    vk0 = *reinterpret_cast<const short8*>(Kst);
    vk1 = *reinterpret_cast<const short8*>(Kst + 8);
    vv0 = *reinterpret_cast<const short8*>(Vst);
    vv1 = *reinterpret_cast<const short8*>(Vst + 8);
    for (int kb = 0; kb < nkb; ++kb) {
        BAR_LGKM();
        *reinterpret_cast<short8*>(lK + sslot0) = vk0;
        *reinterpret_cast<short8*>(lK + sslot1) = vk1;
        *reinterpret_cast<short8*>(lV + sslot0) = vv0;
        *reinterpret_cast<short8*>(lV + sslot1) = vv1;
        if (kb + 1 < nkb) {
            const short* kn = Kst + ((size_t)(kb + 1) << 12);
            const short* vn = Vst + ((kb + 1) << 6);
            vk0 = *reinterpret_cast<const short8*>(kn);
            vk1 = *reinterpret_cast<const short8*>(kn + 8);
            vv0 = *reinterpret_cast<const short8*>(vn);
            vv1 = *reinterpret_cast<const short8*>(vn + 8);
        }
        BAR_LGKM();
        f32x4 acc[4] = {};
        #pragma unroll
        for (int t4 = 0; t4 < 4; ++t4) {
            short8 bk0 = ldfrag(lK, t4 * 16 + lr, lg);
            short8 bk1 = ldfrag(lK, t4 * 16 + lr, lg + 4);
            acc[t4] = __builtin_amdgcn_mfma_f32_16x16x32_bf16(aq0, bk0, acc[t4], 0, 0, 0);
            acc[t4] = __builtin_amdgcn_mfma_f32_16x16x32_bf16(aq1, bk1, acc[t4], 0, 0, 0);
        }
        const bool diag = (kb == qt);
        // P (bf16) -> wave-private LDS, chunk-8 XOR swizzle
        #pragma unroll
        for (int t4 = 0; t4 < 4; ++t4) {
            const int cl = t4 * 16 + lr;
            const int cabs = kb * 64 + cl;
            #pragma unroll
            for (int r = 0; r < 4; ++r) {
                float p;
                if (diag && cabs > rloc + r) p = 0.f;
                else p = exp2f(acc[t4][r] * SC) * rsum[r];
                const int prow = (lg << 2) + r;
                lPw[(prow << 6) + (((t4 * 2 + (lr >> 3)) ^ (prow & 7)) << 3) + (l & 7)] = bf16b(p);
            }
        }
        WAVE_FENCE();   // cross-lane lPw RAW
        // wide attn store: read bf16 quads, upconvert, 4x dwordx4 per lane
        {
            float* abase = attn + ((size_t)bh * S_ + q0 + wrow) * S_ + kb * 64;
            const int colc = (l & 15) << 2;
            const int ch0  = (l & 15) >> 1;
            const int half = ((l & 15) & 1) << 2;
            #pragma unroll
            for (int rr = 0; rr < 4; ++rr) {
                const int row = (l >> 4) + (rr << 2);
                short4v p4 = *reinterpret_cast<const short4v*>(
                    lPw + (row << 6) + ((ch0 ^ (row & 7)) << 3) + half);
                f32x4 pv = {bf2f(p4[0]), bf2f(p4[1]), bf2f(p4[2]), bf2f(p4[3])};
                *reinterpret_cast<f32x4*>(abase + (size_t)row * S_ + colc) = pv;
            }
        }
        // PV A-fragments: direct bf16 ldfrag
        short8 pa0 = ldfrag(lPw, lr, lg);
        short8 pa1 = ldfrag(lPw, lr, lg + 4);
        #pragma unroll
        for (int td = 0; td < 4; ++td) {
            short8 v0 = ldfrag(lV, td * 16 + lr, lg);
            short8 v1 = ldfrag(lV, td * 16 + lr, lg + 4);
            ctxa[td] = __builtin_amdgcn_mfma_f32_16x16x32_bf16(pa0, v0, ctxa[td], 0, 0, 0);
            ctxa[td] = __builtin_amdgcn_mfma_f32_16x16x32_bf16(pa1, v1, ctxa[td], 0, 0, 0);
        }
    }

    short* cbase = ctxb + ((size_t)(b * S_) + q0 + wrow + (lg << 2)) * DM + (h << 6);
    #pragma unroll
    for (int td = 0; td < 4; ++td)
        #pragma unroll
        for (int r = 0; r < 4; ++r)
            cbase[(size_t)r * DM + td * 16 + lr] = bf16b(ctxa[td][r]);

    // ---- zero-fill masked tail, wide: 16 lanes cover one row ----
    {
        const f32x4 z = {0.f, 0.f, 0.f, 0.f};
        const int zs = (qt + 1) << 6;
        const int colc = (l & 15) << 2;
        #pragma unroll
        for (int rr = 0; rr < 4; ++rr) {
            const int row = q0 + wrow + (l >> 4) + (rr << 2);
            float* rowp = attn + ((size_t)bh * S_ + row) * S_;
            for (int c = zs + colc; c < S_; c += 64)
                *reinterpret_cast<f32x4*>(rowp + c) = z;
        }
    }
}

// ---------------------------------------------------------------------------
extern "C" void kernel_launch(void* const* d_in, const int* in_sizes, int n_in,
                              void* d_out, int out_size, void* d_ws, size_t ws_size,
                              hipStream_t stream) {
    const float* q  = (const float*)d_in[0];
    const float* k  = (const float*)d_in[1];
    const float* v  = (const float*)d_in[2];
    // d_in[3]: causal mask, applied analytically
    const float* wq = (const float*)d_in[4];
    const float* wk = (const float*)d_in[5];
    const float* wv = (const float*)d_in[6];
    const float* wd = (const float*)d_in[7];
    const float* bd = (const float*)d_in[8];

    float* out  = (float*)d_out;
    float* attn = (float*)d_out + (size_t)B_ * S_ * DM;

    char* wsc = (char*)d_ws;
    short* ctxb = (short*)wsc;                                   // 16 MB
    short* wT0 = (short*)(wsc + ((size_t)16 << 20));             // 2 MB each
    short* wT1 = (short*)(wsc + ((size_t)18 << 20));
    short* wT2 = (short*)(wsc + ((size_t)20 << 20));
    short* wT3 = (short*)(wsc + ((size_t)22 << 20));
    short* Qh  = (short*)(wsc + ((size_t)24 << 20));             // 16 MB
    short* Kh  = (short*)(wsc + ((size_t)40 << 20));             // 16 MB
    short* VhT = (short*)(wsc + ((size_t)56 << 20));             // 16 MB

    const dim3 b256(256);
    hipLaunchKernelGGL(tcast, dim3(16, 16), b256, 0, stream, wq, wT0);
    hipLaunchKernelGGL(tcast, dim3(16, 16), b256, 0, stream, wk, wT1);
    hipLaunchKernelGGL(tcast, dim3(16, 16), b256, 0, stream, wv, wT2);
    hipLaunchKernelGGL(tcast, dim3(16, 16), b256, 0, stream, wd, wT3);

    hipLaunchKernelGGL((gemm_nt<0, 1>), dim3(512), b256, 0, stream, q, wT0, nullptr, Qh,  nullptr);
    hipLaunchKernelGGL((gemm_nt<0, 1>), dim3(512), b256, 0, stream, k, wT1, nullptr, Kh,  nullptr);
    hipLaunchKernelGGL((gemm_nt<1, 1>), dim3(512), b256, 0, stream, v, wT2, nullptr, VhT, nullptr);

    hipLaunchKernelGGL(attn_mfma, dim3(2048), b256, 0, stream,
                       Qh, Kh, VhT, attn, ctxb);

    hipLaunchKernelGGL((gemm_nt<2, 0>), dim3(512), b256, 0, stream, ctxb, wT3, bd, nullptr, out);
}

// Round 19
// 419.015 us; speedup vs baseline: 1.7924x; 1.0538x over previous
//
#include <hip/hip_runtime.h>
#include <hip/hip_bf16.h>
#include <math.h>

#define B_  4
#define S_  2048
#define DM  1024
#define H_  16

typedef __attribute__((ext_vector_type(8))) short short8;
typedef __attribute__((ext_vector_type(4))) short short4v;
typedef __attribute__((ext_vector_type(4))) float f32x4;

// lgkm-only barrier: LDS-coherent workgroup sync WITHOUT draining vmcnt.
#define BAR_LGKM() do { \
    asm volatile("s_waitcnt lgkmcnt(0)" ::: "memory"); \
    __builtin_amdgcn_s_barrier(); \
    __builtin_amdgcn_sched_barrier(0); \
} while (0)

// Wave-local LDS fence: order cross-lane ds_write -> ds_read within a wave.
#define WAVE_FENCE() do { \
    asm volatile("s_waitcnt lgkmcnt(0)" ::: "memory"); \
    __builtin_amdgcn_sched_barrier(0); \
} while (0)

// global -> LDS direct DMA, 16 B/lane (pre-swizzled-source pattern).
typedef __attribute__((address_space(3))) short      lds_s;
typedef __attribute__((address_space(1))) const short glb_s;
#define GLD16(g, l) __builtin_amdgcn_global_load_lds((glb_s*)(g), (lds_s*)(l), 16, 0, 0)

__device__ __forceinline__ short bf16b(float f) {
    __hip_bfloat16 h = __float2bfloat16(f);
    short s; __builtin_memcpy(&s, &h, 2);
    return s;
}

__device__ __forceinline__ float bf2f(short s) {
    unsigned int u = ((unsigned int)(unsigned short)s) << 16;
    float f; __builtin_memcpy(&f, &u, 4);
    return f;
}

__device__ __forceinline__ short8 cvt8(float4 a, float4 b) {
    short8 o;
    o[0] = bf16b(a.x); o[1] = bf16b(a.y); o[2] = bf16b(a.z); o[3] = bf16b(a.w);
    o[4] = bf16b(b.x); o[5] = bf16b(b.y); o[6] = bf16b(b.z); o[7] = bf16b(b.w);
    return o;
}

// bf16 LDS tile convention: [row][8 chunks of 8 shorts], chunk c at slot
// c ^ (row & 7). ldfrag(row, c) returns global chunk c (k-offset c*8).
__device__ __forceinline__ short8 ldfrag(const short* __restrict__ lds, int row, int c) {
    return *reinterpret_cast<const short8*>(lds + (((row << 3) + (c ^ (row & 7))) << 3));
}

// ---------------------------------------------------------------------------
// ALL four W fp32 [K][N] -> WT bf16 [N][K], one launch (z selects weight).
// ---------------------------------------------------------------------------
__global__ __launch_bounds__(256)
void tcast4(const float* __restrict__ W0, const float* __restrict__ W1,
            const float* __restrict__ W2, const float* __restrict__ W3,
            short* __restrict__ WT) {
    __shared__ float tile[64][65];
    const int z = blockIdx.z;
    const float* W = (z == 0) ? W0 : (z == 1) ? W1 : (z == 2) ? W2 : W3;
    short* out = WT + ((size_t)z << 20);
    const int n0 = blockIdx.x << 6, k0 = blockIdx.y << 6;
    const int t = threadIdx.x;
    #pragma unroll
    for (int i = 0; i < 16; ++i) {
        int f = i * 256 + t, r = f >> 6, c = f & 63;
        tile[r][c] = W[(size_t)(k0 + r) * DM + n0 + c];
    }
    __syncthreads();
    #pragma unroll
    for (int i = 0; i < 16; ++i) {
        int f = i * 256 + t, r = f >> 6, c = f & 63;
        out[(size_t)(n0 + r) * DM + k0 + c] = bf16b(tile[c][r]);
    }
}

// ---------------------------------------------------------------------------
// ALL three projections in one launch: grid 1536, g = id>>9 selects {q,k,v};
// body = frozen round-14 GEMM (fp32-A reg-cast staging + B via gload_lds).
// Epilogue: g<2 -> bf16 headsplit [b,h,s,d]; g==2 -> headsplit-T [b,h,d,s].
// ---------------------------------------------------------------------------
__global__ __launch_bounds__(256)
void gemm_proj(const float* __restrict__ qin, const float* __restrict__ kin,
               const float* __restrict__ vin, const short* __restrict__ wT,
               short* __restrict__ Qh, short* __restrict__ Kh,
               short* __restrict__ VhT) {
    __shared__ __align__(16) short lA[128 * 64];
    __shared__ __align__(16) short lB[128 * 64];
    const int K = 1024;
    const int id = blockIdx.x;
    const int g = id >> 9, sub = id & 511;
    const float* A32 = (g == 0) ? qin : (g == 1) ? kin : vin;
    const short* BT = wT + ((size_t)g << 20);
    short* Cb = (g == 0) ? Qh : (g == 1) ? Kh : VhT;

    const int swz = ((sub & 7) << 6) + (sub >> 3);   // XCD-aware, 512 % 8 == 0
    const int bm = swz >> 3, bn = swz & 7;
    const int t = threadIdx.x, w = t >> 6, l = t & 63, lg = l >> 4, lr = l & 15;
    const int wm = w >> 1, wn = w & 1;

    const int srow = t >> 1, sw = srow & 7, codd = t & 1;
    const size_t arow = (size_t)(bm * 128 + srow) * K;
    short* la = lA + (srow << 6);

    const int grow = l >> 3;
    const int gcol = ((l & 7) ^ grow) << 3;
    const short* Bg  = BT + (size_t)(bn * 128 + w * 32 + grow) * K + gcol;
    short*       lBw = lB + ((w * 32) << 6);

    f32x4 acc[4][4] = {};
    float4 fa[4][2];
    #pragma unroll
    for (int j = 0; j < 4; ++j) {
        const float* p = A32 + arow + ((codd + (j << 1)) << 3);
        fa[j][0] = *reinterpret_cast<const float4*>(p);
        fa[j][1] = *reinterpret_cast<const float4*>(p + 4);
    }

    for (int k0 = 0; k0 < K; k0 += 64) {
        __syncthreads();
        #pragma unroll
        for (int j = 0; j < 4; ++j) {
            const int c = (codd + (j << 1)) ^ sw;
            *reinterpret_cast<short8*>(la + (c << 3)) = cvt8(fa[j][0], fa[j][1]);
        }
        #pragma unroll
        for (int i = 0; i < 4; ++i)
            GLD16(Bg + k0 + (size_t)(i << 3) * K, lBw + (i << 9));
        __syncthreads();
        if (k0 + 64 < K) {
            #pragma unroll
            for (int j = 0; j < 4; ++j) {
                const float* p = A32 + arow + k0 + 64 + ((codd + (j << 1)) << 3);
                fa[j][0] = *reinterpret_cast<const float4*>(p);
                fa[j][1] = *reinterpret_cast<const float4*>(p + 4);
            }
        }
        #pragma unroll
        for (int kk = 0; kk < 2; ++kk) {
            short8 af[4], bfr[4];
            #pragma unroll
            for (int fm = 0; fm < 4; ++fm) af[fm]  = ldfrag(lA, wm * 64 + fm * 16 + lr, kk * 4 + lg);
            #pragma unroll
            for (int fn = 0; fn < 4; ++fn) bfr[fn] = ldfrag(lB, wn * 64 + fn * 16 + lr, kk * 4 + lg);
            #pragma unroll
            for (int fm = 0; fm < 4; ++fm)
                #pragma unroll
                for (int fn = 0; fn < 4; ++fn)
                    acc[fm][fn] = __builtin_amdgcn_mfma_f32_16x16x32_bf16(af[fm], bfr[fn], acc[fm][fn], 0, 0, 0);
        }
    }

    const int rb = bm * 128 + wm * 64 + (lg << 2);
    const int cb = bn * 128 + wn * 64 + lr;
    #pragma unroll
    for (int fm = 0; fm < 4; ++fm) {
        #pragma unroll
        for (int fn = 0; fn < 4; ++fn) {
            const int col = cb + fn * 16;
            const int h = col >> 6, d = col & 63;
            if (g < 2) {
                #pragma unroll
                for (int r = 0; r < 4; ++r) {
                    const int row = rb + fm * 16 + r;
                    const int b = row >> 11, s = row & 2047;
                    Cb[(((size_t)(b * H_ + h) * S_ + s) << 6) + d] = bf16b(acc[fm][fn][r]);
                }
            } else {
                const int row0 = rb + fm * 16;
                const int b = row0 >> 11, s = row0 & 2047;
                short4v pk;
                #pragma unroll
                for (int r = 0; r < 4; ++r) pk[r] = bf16b(acc[fm][fn][r]);
                *reinterpret_cast<short4v*>(Cb + (((size_t)(b * H_ + h) << 6) + d) * S_ + s) = pk;
            }
        }
    }
}

// ---------------------------------------------------------------------------
// Final GEMM: out = ctx(bf16) @ wd^T + bd, fp32 out. A AND B via gload_lds.
// ---------------------------------------------------------------------------
__global__ __launch_bounds__(256)
void gemm_out(const short* __restrict__ A16, const short* __restrict__ BT,
              const float* __restrict__ bias, float* __restrict__ Cf) {
    __shared__ __align__(16) short lA[128 * 64];
    __shared__ __align__(16) short lB[128 * 64];
    const int K = 1024;
    const int id = blockIdx.x;
    const int swz = ((id & 7) << 6) + (id >> 3);
    const int bm = swz >> 3, bn = swz & 7;
    const int t = threadIdx.x, w = t >> 6, l = t & 63, lg = l >> 4, lr = l & 15;
    const int wm = w >> 1, wn = w & 1;

    const int grow = l >> 3;
    const int gcol = ((l & 7) ^ grow) << 3;
    const short* Bg  = BT + (size_t)(bn * 128 + w * 32 + grow) * K + gcol;
    short*       lBw = lB + ((w * 32) << 6);
    const short* Ag  = A16 + (size_t)(bm * 128 + w * 32 + grow) * K + gcol;
    short*       lAw = lA + ((w * 32) << 6);

    f32x4 acc[4][4] = {};
    for (int k0 = 0; k0 < K; k0 += 64) {
        __syncthreads();
        #pragma unroll
        for (int i = 0; i < 4; ++i) {
            GLD16(Ag + k0 + (size_t)(i << 3) * K, lAw + (i << 9));
            GLD16(Bg + k0 + (size_t)(i << 3) * K, lBw + (i << 9));
        }
        __syncthreads();
        #pragma unroll
        for (int kk = 0; kk < 2; ++kk) {
            short8 af[4], bfr[4];
            #pragma unroll
            for (int fm = 0; fm < 4; ++fm) af[fm]  = ldfrag(lA, wm * 64 + fm * 16 + lr, kk * 4 + lg);
            #pragma unroll
            for (int fn = 0; fn < 4; ++fn) bfr[fn] = ldfrag(lB, wn * 64 + fn * 16 + lr, kk * 4 + lg);
            #pragma unroll
            for (int fm = 0; fm < 4; ++fm)
                #pragma unroll
                for (int fn = 0; fn < 4; ++fn)
                    acc[fm][fn] = __builtin_amdgcn_mfma_f32_16x16x32_bf16(af[fm], bfr[fn], acc[fm][fn], 0, 0, 0);
        }
    }

    const int rb = bm * 128 + wm * 64 + (lg << 2);
    const int cb = bn * 128 + wn * 64 + lr;
    #pragma unroll
    for (int fm = 0; fm < 4; ++fm) {
        #pragma unroll
        for (int fn = 0; fn < 4; ++fn) {
            const int col = cb + fn * 16;
            const float bv = bias[col];
            #pragma unroll
            for (int r = 0; r < 4; ++r) {
                const int row = rb + fm * 16 + r;
                Cf[(size_t)row * DM + col] = acc[fm][fn][r] + bv;
            }
        }
    }
}

// ---------------------------------------------------------------------------
// bf16 MFMA causal attention (FROZEN from round 18): 64 q-rows/block, 4 waves,
// 256 threads, 24 KB LDS, XCD-clustered grid, WAVE_FENCE on lP RAW.
// ---------------------------------------------------------------------------
__global__ __launch_bounds__(256, 4)
void attn_mfma(const short* __restrict__ Qh, const short* __restrict__ Kh,
               const short* __restrict__ VhT, float* __restrict__ attn,
               short* __restrict__ ctxb) {
    __shared__ __align__(16) short smem[64 * 64 * 2 + 4 * 16 * 64];  // 24 KB
    short* lQ = smem;               // [64*64] bf16 (staging phase, aliases lK)
    short* lK = smem;
    short* lV = smem + 64 * 64;
    short* lP = smem + 64 * 64 * 2; // 4 waves x [16][64] bf16

    const int t = threadIdx.x, w = t >> 6, l = t & 63, lg = l >> 4, lr = l & 15;
    const int n   = (int)blockIdx.x;
    const int xcd = n & 7, rest = n >> 3;
    const int j   = rest & 31, mh = rest >> 5;
    const int bh  = (mh << 3) | xcd;
    const int qt  = 31 - j;
    const int q0  = qt << 6;
    const int h   = bh & 15, b = bh >> 4;
    const float SC = 0.18033688f;   // log2(e)/8

    const short* Qg = Qh  + (((size_t)bh * S_ + q0) << 6);
    const short* Kg = Kh  + ((size_t)bh * S_ << 6);
    const short* Vg = VhT + ((size_t)bh << 6) * S_;

    const int wrow = w * 16;
    const int rloc = q0 + wrow + (lg << 2);
    const int nkb = qt + 1;

    const int srow = t >> 2, sc0 = (t & 3) << 1, ssw = srow & 7;
    const int sslot0 = ((srow << 3) + ((sc0    ) ^ ssw)) << 3;
    const int sslot1 = ((srow << 3) + ((sc0 + 1) ^ ssw)) << 3;
    const short* Kst = Kg + (srow << 6) + (sc0 << 3);
    const short* Vst = Vg + (size_t)srow * S_ + (sc0 << 3);

    {
        const short* src = Qg + (srow << 6) + (sc0 << 3);
        short8 v0 = *reinterpret_cast<const short8*>(src);
        short8 v1 = *reinterpret_cast<const short8*>(src + 8);
        *reinterpret_cast<short8*>(lQ + sslot0) = v0;
        *reinterpret_cast<short8*>(lQ + sslot1) = v1;
    }
    __syncthreads();

    const short8 aq0 = ldfrag(lQ, wrow + lr, lg);
    const short8 aq1 = ldfrag(lQ, wrow + lr, lg + 4);

    // ---------------- pass A: row sums of exp ----------------
    float rsum[4] = {0.f, 0.f, 0.f, 0.f};
    short8 vk0 = *reinterpret_cast<const short8*>(Kst);
    short8 vk1 = *reinterpret_cast<const short8*>(Kst + 8);
    for (int kb = 0; kb < nkb; ++kb) {
        BAR_LGKM();
        *reinterpret_cast<short8*>(lK + sslot0) = vk0;
        *reinterpret_cast<short8*>(lK + sslot1) = vk1;
        if (kb + 1 < nkb) {
            vk0 = *reinterpret_cast<const short8*>(Kst + ((size_t)(kb + 1) << 12));
            vk1 = *reinterpret_cast<const short8*>(Kst + ((size_t)(kb + 1) << 12) + 8);
        }
        BAR_LGKM();
        f32x4 acc[4] = {};
        #pragma unroll
        for (int t4 = 0; t4 < 4; ++t4) {
            short8 bk0 = ldfrag(lK, t4 * 16 + lr, lg);
            short8 bk1 = ldfrag(lK, t4 * 16 + lr, lg + 4);
            acc[t4] = __builtin_amdgcn_mfma_f32_16x16x32_bf16(aq0, bk0, acc[t4], 0, 0, 0);
            acc[t4] = __builtin_amdgcn_mfma_f32_16x16x32_bf16(aq1, bk1, acc[t4], 0, 0, 0);
        }
        if (kb < qt) {
            #pragma unroll
            for (int t4 = 0; t4 < 4; ++t4)
                #pragma unroll
                for (int r = 0; r < 4; ++r)
                    rsum[r] += exp2f(acc[t4][r] * SC);
        } else {
            #pragma unroll
            for (int t4 = 0; t4 < 4; ++t4) {
                const int cabs = kb * 64 + t4 * 16 + lr;
                #pragma unroll
                for (int r = 0; r < 4; ++r)
                    if (cabs <= rloc + r) rsum[r] += exp2f(acc[t4][r] * SC);
            }
        }
    }
    #pragma unroll
    for (int r = 0; r < 4; ++r) {
        #pragma unroll
        for (int m = 1; m < 16; m <<= 1) rsum[r] += __shfl_xor(rsum[r], m);
        rsum[r] = 1.f / rsum[r];
    }

    // ---------------- pass B: attn write (wide) + PV ----------------
    f32x4 ctxa[4] = {};
    short* lPw = lP + (w << 10);
    short8 vv0, vv1;
    vk0 = *reinterpret_cast<const short8*>(Kst);
    vk1 = *reinterpret_cast<const short8*>(Kst + 8);
    vv0 = *reinterpret_cast<const short8*>(Vst);
    vv1 = *reinterpret_cast<const short8*>(Vst + 8);
    for (int kb = 0; kb < nkb; ++kb) {
        BAR_LGKM();
        *reinterpret_cast<short8*>(lK + sslot0) = vk0;
        *reinterpret_cast<short8*>(lK + sslot1) = vk1;
        *reinterpret_cast<short8*>(lV + sslot0) = vv0;
        *reinterpret_cast<short8*>(lV + sslot1) = vv1;
        if (kb + 1 < nkb) {
            const short* kn = Kst + ((size_t)(kb + 1) << 12);
            const short* vn = Vst + ((kb + 1) << 6);
            vk0 = *reinterpret_cast<const short8*>(kn);
            vk1 = *reinterpret_cast<const short8*>(kn + 8);
            vv0 = *reinterpret_cast<const short8*>(vn);
            vv1 = *reinterpret_cast<const short8*>(vn + 8);
        }
        BAR_LGKM();
        f32x4 acc[4] = {};
        #pragma unroll
        for (int t4 = 0; t4 < 4; ++t4) {
            short8 bk0 = ldfrag(lK, t4 * 16 + lr, lg);
            short8 bk1 = ldfrag(lK, t4 * 16 + lr, lg + 4);
            acc[t4] = __builtin_amdgcn_mfma_f32_16x16x32_bf16(aq0, bk0, acc[t4], 0, 0, 0);
            acc[t4] = __builtin_amdgcn_mfma_f32_16x16x32_bf16(aq1, bk1, acc[t4], 0, 0, 0);
        }
        const bool diag = (kb == qt);
        #pragma unroll
        for (int t4 = 0; t4 < 4; ++t4) {
            const int cl = t4 * 16 + lr;
            const int cabs = kb * 64 + cl;
            #pragma unroll
            for (int r = 0; r < 4; ++r) {
                float p;
                if (diag && cabs > rloc + r) p = 0.f;
                else p = exp2f(acc[t4][r] * SC) * rsum[r];
                const int prow = (lg << 2) + r;
                lPw[(prow << 6) + (((t4 * 2 + (lr >> 3)) ^ (prow & 7)) << 3) + (l & 7)] = bf16b(p);
            }
        }
        WAVE_FENCE();   // cross-lane lPw RAW
        {
            float* abase = attn + ((size_t)bh * S_ + q0 + wrow) * S_ + kb * 64;
            const int colc = (l & 15) << 2;
            const int ch0  = (l & 15) >> 1;
            const int half = ((l & 15) & 1) << 2;
            #pragma unroll
            for (int rr = 0; rr < 4; ++rr) {
                const int row = (l >> 4) + (rr << 2);
                short4v p4 = *reinterpret_cast<const short4v*>(
                    lPw + (row << 6) + ((ch0 ^ (row & 7)) << 3) + half);
                f32x4 pv = {bf2f(p4[0]), bf2f(p4[1]), bf2f(p4[2]), bf2f(p4[3])};
                *reinterpret_cast<f32x4*>(abase + (size_t)row * S_ + colc) = pv;
            }
        }
        short8 pa0 = ldfrag(lPw, lr, lg);
        short8 pa1 = ldfrag(lPw, lr, lg + 4);
        #pragma unroll
        for (int td = 0; td < 4; ++td) {
            short8 v0 = ldfrag(lV, td * 16 + lr, lg);
            short8 v1 = ldfrag(lV, td * 16 + lr, lg + 4);
            ctxa[td] = __builtin_amdgcn_mfma_f32_16x16x32_bf16(pa0, v0, ctxa[td], 0, 0, 0);
            ctxa[td] = __builtin_amdgcn_mfma_f32_16x16x32_bf16(pa1, v1, ctxa[td], 0, 0, 0);
        }
    }

    short* cbase = ctxb + ((size_t)(b * S_) + q0 + wrow + (lg << 2)) * DM + (h << 6);
    #pragma unroll
    for (int td = 0; td < 4; ++td)
        #pragma unroll
        for (int r = 0; r < 4; ++r)
            cbase[(size_t)r * DM + td * 16 + lr] = bf16b(ctxa[td][r]);

    {
        const f32x4 z = {0.f, 0.f, 0.f, 0.f};
        const int zs = (qt + 1) << 6;
        const int colc = (l & 15) << 2;
        #pragma unroll
        for (int rr = 0; rr < 4; ++rr) {
            const int row = q0 + wrow + (l >> 4) + (rr << 2);
            float* rowp = attn + ((size_t)bh * S_ + row) * S_;
            for (int c = zs + colc; c < S_; c += 64)
                *reinterpret_cast<f32x4*>(rowp + c) = z;
        }
    }
}

// ---------------------------------------------------------------------------
extern "C" void kernel_launch(void* const* d_in, const int* in_sizes, int n_in,
                              void* d_out, int out_size, void* d_ws, size_t ws_size,
                              hipStream_t stream) {
    const float* q  = (const float*)d_in[0];
    const float* k  = (const float*)d_in[1];
    const float* v  = (const float*)d_in[2];
    // d_in[3]: causal mask, applied analytically
    const float* wq = (const float*)d_in[4];
    const float* wk = (const float*)d_in[5];
    const float* wv = (const float*)d_in[6];
    const float* wd = (const float*)d_in[7];
    const float* bd = (const float*)d_in[8];

    float* out  = (float*)d_out;
    float* attn = (float*)d_out + (size_t)B_ * S_ * DM;

    char* wsc = (char*)d_ws;
    short* ctxb = (short*)wsc;                                   // 16 MB
    short* wT   = (short*)(wsc + ((size_t)16 << 20));            // 4 x 2 MB (wq,wk,wv,wd)
    short* Qh   = (short*)(wsc + ((size_t)24 << 20));            // 16 MB
    short* Kh   = (short*)(wsc + ((size_t)40 << 20));            // 16 MB
    short* VhT  = (short*)(wsc + ((size_t)56 << 20));            // 16 MB

    const dim3 b256(256);
    hipLaunchKernelGGL(tcast4, dim3(16, 16, 4), b256, 0, stream, wq, wk, wv, wd, wT);
    hipLaunchKernelGGL(gemm_proj, dim3(1536), b256, 0, stream, q, k, v, wT, Qh, Kh, VhT);
    hipLaunchKernelGGL(attn_mfma, dim3(2048), b256, 0, stream, Qh, Kh, VhT, attn, ctxb);
    hipLaunchKernelGGL(gemm_out, dim3(512), b256, 0, stream,
                       ctxb, wT + ((size_t)3 << 20), bd, out);
}